// Round 3
// baseline (835.244 us; speedup 1.0000x reference)
//
#include <hip/hip_runtime.h>
#include <hip/hip_bf16.h>

// SlotAttention fused pipeline for MI355X (gfx950).
// B=64, O=11, L=4096, M=S=256, H=1024, 2 iterations.
// Strategy: bf16 MFMA (16x16x32) for all matmuls, fp32 accum + fp32 pointwise.
// Inverted softmax (over O) is column-local -> fully streaming attention pass.

using f32x4 = __attribute__((ext_vector_type(4))) float;
using s16x8 = __attribute__((ext_vector_type(8))) short;

#define MFMA_B16(a,b,c) __builtin_amdgcn_mfma_f32_16x16x32_bf16((a),(b),(c),0,0,0)

static __device__ __forceinline__ short f2bf(float f) {
  union { __hip_bfloat16 h; short s; } u; u.h = __float2bfloat16(f); return u.s;
}
static __device__ __forceinline__ s16x8 zero8() {
  s16x8 z;
#pragma unroll
  for (int i = 0; i < 8; i++) z[i] = 0;
  return z;
}

// ---------------- workspace layout (bytes) ----------------
enum : size_t {
  OFF_WKB  = 0,
  OFF_WVB  = OFF_WKB + 131072,          // 256*256 bf16
  OFF_WQB  = OFF_WVB + 131072,
  OFF_WIB  = OFF_WQB + 131072,
  OFF_WHB  = OFF_WIB + 393216,          // 768*256 bf16
  OFF_W1B  = OFF_WHB + 393216,
  OFF_W2B  = OFF_W1B + 524288,          // 1024*256 bf16
  OFF_QB   = OFF_W2B + 524288,
  OFF_UPDB = OFF_QB  + 360448,          // 704*256 bf16
  OFF_SAF  = OFF_UPDB + 360448,
  OFF_SAB  = OFF_SAF + 720896,          // 704*256 f32
  OFF_SBF  = OFF_SAB + 360448,
  OFF_SBB  = OFF_SBF + 720896,
  OFF_HIDB = OFF_SBB + 360448,
  OFF_NUM  = OFF_HIDB + 1441792,        // 704*1024 bf16
  OFF_DEN  = OFF_NUM + 720896,
  OFF_KB   = OFF_DEN + 3072,
  OFF_VB   = OFF_KB + 134217728,        // 64*4096*256 bf16
  WS_NEED  = OFF_VB + 134217728
};

// ---------------- prep: cast weights to bf16, init slot buffers ----------------
__global__ __launch_bounds__(256) void prep_kernel(
    const float* __restrict__ Wk, const float* __restrict__ Wv, const float* __restrict__ Wq,
    const float* __restrict__ Wi, const float* __restrict__ Wh,
    const float* __restrict__ W1, const float* __restrict__ W2,
    const float* __restrict__ slots,
    short* __restrict__ WkB, short* __restrict__ WvB, short* __restrict__ WqB,
    short* __restrict__ WiB, short* __restrict__ WhB,
    short* __restrict__ W1B, short* __restrict__ W2B,
    float* __restrict__ SaF, short* __restrict__ SaB)
{
  int idx = blockIdx.x * 256 + threadIdx.x;
  int stride = gridDim.x * 256;
  for (int i = idx; i < 256*256; i += stride) { WkB[i]=f2bf(Wk[i]); WvB[i]=f2bf(Wv[i]); WqB[i]=f2bf(Wq[i]); }
  for (int i = idx; i < 768*256; i += stride) { WiB[i]=f2bf(Wi[i]); WhB[i]=f2bf(Wh[i]); }
  for (int i = idx; i < 1024*256; i += stride) { W1B[i]=f2bf(W1[i]); W2B[i]=f2bf(W2[i]); }
  for (int i = idx; i < 704*256; i += stride) { float v = slots[i]; SaF[i]=v; SaB[i]=f2bf(v); }
}

// ---------------- fused LN(inputs) + K/V GEMM ----------------
// grid (32 Ltiles, 64 B), block 256 (4 waves). k -> [B,L,S] bf16 ; v -> [B,S,L] bf16 (transposed).
__global__ __launch_bounds__(256) void kv_kernel(
    const float* __restrict__ inputs, const float* __restrict__ lng, const float* __restrict__ lnb,
    const short* __restrict__ WkB, const short* __restrict__ WvB,
    short* __restrict__ kB, short* __restrict__ vB)
{
  __shared__ short xt[128][264];   // +8 pad: stride 528B = 4 banks -> conflict-free b128 reads
  const int b = blockIdx.y;
  const int l0 = blockIdx.x * 128;
  const int tid = threadIdx.x;
  const int w = tid >> 6, lane = tid & 63;
  const int grp = lane >> 4, li = lane & 15;

  // LN phase: one wave per row, 32 rows each
  float4 g4 = *(const float4*)(lng + lane*4);
  float4 b4 = *(const float4*)(lnb + lane*4);
  for (int i = 0; i < 32; i++) {
    int row = w*32 + i;
    const float4 x = *(const float4*)(inputs + ((size_t)(b*4096 + l0 + row))*256 + lane*4);
    float s = x.x+x.y+x.z+x.w;
    float ss = x.x*x.x + x.y*x.y + x.z*x.z + x.w*x.w;
#pragma unroll
    for (int m = 1; m < 64; m <<= 1) { s += __shfl_xor(s, m); ss += __shfl_xor(ss, m); }
    float mu = s * 0.00390625f;
    float rs = rsqrtf(ss*0.00390625f - mu*mu + 1e-6f);
    short4 o;
    o.x = f2bf((x.x-mu)*rs*g4.x + b4.x);
    o.y = f2bf((x.y-mu)*rs*g4.y + b4.y);
    o.z = f2bf((x.z-mu)*rs*g4.z + b4.z);
    o.w = f2bf((x.w-mu)*rs*g4.w + b4.w);
    *(short4*)(&xt[row][lane*4]) = o;
  }
  __syncthreads();

  // GEMM phase: wave w covers 128 output cols: w0/w1 -> Wk cols, w2/w3 -> Wv cols
  const short* Wbase = (w < 2) ? WkB : WvB;
  const int nwave = (w & 1) * 128;
  for (int nt = 0; nt < 8; nt++) {
    const int ncol = nwave + nt*16 + li;
    s16x8 bw[8];
    const short* wp = Wbase + (size_t)ncol*256 + grp*8;
#pragma unroll
    for (int kt = 0; kt < 8; kt++) bw[kt] = *(const s16x8*)(wp + kt*32);
    for (int mp = 0; mp < 4; mp++) {
      s16x8 a0[8], a1[8];
#pragma unroll
      for (int kt = 0; kt < 8; kt++) {
        a0[kt] = *(const s16x8*)(&xt[mp*32 + li][kt*32 + grp*8]);
        a1[kt] = *(const s16x8*)(&xt[mp*32 + 16 + li][kt*32 + grp*8]);
      }
      f32x4 c0 = {0,0,0,0}, c1 = {0,0,0,0};
#pragma unroll
      for (int kt = 0; kt < 8; kt++) {
        c0 = MFMA_B16(a0[kt], bw[kt], c0);
        c1 = MFMA_B16(a1[kt], bw[kt], c1);
      }
      const int row0 = mp*32 + grp*4;
      if (w < 2) {
#pragma unroll
        for (int r = 0; r < 4; r++) {
          kB[((size_t)(b*4096 + l0 + row0 + r))*256 + ncol]      = f2bf(c0[r]);
          kB[((size_t)(b*4096 + l0 + row0 + 16 + r))*256 + ncol] = f2bf(c1[r]);
        }
      } else {
        short4 p0, p1;
        p0.x=f2bf(c0[0]); p0.y=f2bf(c0[1]); p0.z=f2bf(c0[2]); p0.w=f2bf(c0[3]);
        p1.x=f2bf(c1[0]); p1.y=f2bf(c1[1]); p1.z=f2bf(c1[2]); p1.w=f2bf(c1[3]);
        short* vp = vB + ((size_t)(b*256 + ncol))*4096 + l0 + row0;
        *(short4*)vp = p0;
        *(short4*)(vp + 16) = p1;
      }
    }
  }
}

// ---------------- LN(slots) + q = sn@Wq.T * scale ; also zero num/den accumulators ----------------
// grid (44, 4), block 256
__global__ __launch_bounds__(256) void slotpre_kernel(
    const float* __restrict__ SaF, const float* __restrict__ lng, const float* __restrict__ lnb,
    const short* __restrict__ WqB, short* __restrict__ qB,
    float* __restrict__ numF, float* __restrict__ denF)
{
  __shared__ float red0[16][16], red1[16][16];
  __shared__ float mu_s[16], rs_s[16];
  __shared__ short hl[16][264];
  const int mt = blockIdx.x, nb = blockIdx.y;
  const int tid = threadIdx.x;
  { // zero the attention accumulators (used later in stream order)
    int gidx = (blockIdx.y*44 + blockIdx.x)*256 + tid;
    for (int i = gidx; i < 704*256; i += 44*4*256) numF[i] = 0.0f;
    if (gidx < 704) denF[gidx] = 0.0f;
  }
  const int rr = tid & 15, cs = tid >> 4;
  const float* rp = SaF + (size_t)(mt*16 + rr)*256 + cs*16;
  float s = 0.f, ss = 0.f;
#pragma unroll
  for (int i = 0; i < 16; i++) { float x = rp[i]; s += x; ss += x*x; }
  red0[rr][cs] = s; red1[rr][cs] = ss;
  __syncthreads();
  if (tid < 16) {
    float ts = 0.f, tss = 0.f;
#pragma unroll
    for (int i = 0; i < 16; i++) { ts += red0[tid][i]; tss += red1[tid][i]; }
    float mu = ts * 0.00390625f;
    mu_s[tid] = mu; rs_s[tid] = rsqrtf(tss*0.00390625f - mu*mu + 1e-6f);
  }
  __syncthreads();
  {
    float mu = mu_s[rr], rs = rs_s[rr];
#pragma unroll
    for (int i = 0; i < 16; i++) { int c = cs*16 + i; hl[rr][c] = f2bf((rp[i]-mu)*rs*lng[c] + lnb[c]); }
  }
  __syncthreads();
  const int w = tid >> 6, lane = tid & 63, grp = lane >> 4, li = lane & 15;
  const int n = nb*64 + w*16 + li;
  f32x4 acc = {0,0,0,0};
  const short* wp = WqB + (size_t)n*256 + grp*8;
#pragma unroll
  for (int kt = 0; kt < 8; kt++)
    acc = MFMA_B16(*(const s16x8*)(&hl[li][kt*32 + grp*8]), *(const s16x8*)(wp + kt*32), acc);
#pragma unroll
  for (int r = 0; r < 4; r++)
    qB[(size_t)(mt*16 + grp*4 + r)*256 + n] = f2bf(acc[r] * 0.0625f);  // scale = 256^-0.5
}

// ---------------- streaming attention: logits -> inverted softmax -> P@V partials ----------------
// grid (8 Lchunks, 64 B), block 256. Each wave handles 128 l's (4 pairs of 16-col tiles).
__global__ __launch_bounds__(256) void attn_kernel(
    const short* __restrict__ qB, const short* __restrict__ kB, const short* __restrict__ vB,
    float* __restrict__ numF, float* __restrict__ denF,
    float* __restrict__ attn_out, const int write_attn)
{
  __shared__ short plds[4][16][40];  // per-wave P-transpose buffer, 80B row stride (16B aligned)
  const int b = blockIdx.y;
  const int tid = threadIdx.x;
  const int w = tid >> 6, lane = tid & 63, grp = lane >> 4, li = lane & 15;
  const int nvalid = (grp < 2) ? 4 : (grp == 2 ? 3 : 0);  // q rows 0..10 valid

  s16x8 aq[8];
  if (li < 11) {
    const short* qp = qB + (size_t)(b*11 + li)*256 + grp*8;
#pragma unroll
    for (int kt = 0; kt < 8; kt++) aq[kt] = *(const s16x8*)(qp + kt*32);
  } else {
#pragma unroll
    for (int kt = 0; kt < 8; kt++) aq[kt] = zero8();
  }
  f32x4 zf = {0,0,0,0};
  f32x4 accu[16];
#pragma unroll
  for (int st = 0; st < 16; st++) accu[st] = zf;
  float dacc[4] = {0.f, 0.f, 0.f, 0.f};

  for (int p = 0; p < 4; p++) {
    const int l0 = blockIdx.x*512 + w*128 + p*32;
    f32x4 c0 = zf, c1 = zf;
    const short* kp = kB + ((size_t)(b*4096 + l0 + li))*256 + grp*8;
#pragma unroll
    for (int kt = 0; kt < 8; kt++) c0 = MFMA_B16(aq[kt], *(const s16x8*)(kp + kt*32), c0);
#pragma unroll
    for (int kt = 0; kt < 8; kt++) c1 = MFMA_B16(aq[kt], *(const s16x8*)(kp + 16*256 + kt*32), c1);

    float a0[4], a1[4];
    {
      float mx = -1e30f;
#pragma unroll
      for (int r = 0; r < 4; r++) if (r < nvalid) mx = fmaxf(mx, c0[r]);
      mx = fmaxf(mx, __shfl_xor(mx, 16)); mx = fmaxf(mx, __shfl_xor(mx, 32));
      float sm = 0.f;
#pragma unroll
      for (int r = 0; r < 4; r++) { a0[r] = (r < nvalid) ? __expf(c0[r]-mx) : 0.f; sm += a0[r]; }
      sm += __shfl_xor(sm, 16); sm += __shfl_xor(sm, 32);
      float inv = 1.0f / sm;
#pragma unroll
      for (int r = 0; r < 4; r++) { a0[r] *= inv; dacc[r] += a0[r]; }
    }
    {
      float mx = -1e30f;
#pragma unroll
      for (int r = 0; r < 4; r++) if (r < nvalid) mx = fmaxf(mx, c1[r]);
      mx = fmaxf(mx, __shfl_xor(mx, 16)); mx = fmaxf(mx, __shfl_xor(mx, 32));
      float sm = 0.f;
#pragma unroll
      for (int r = 0; r < 4; r++) { a1[r] = (r < nvalid) ? __expf(c1[r]-mx) : 0.f; sm += a1[r]; }
      sm += __shfl_xor(sm, 16); sm += __shfl_xor(sm, 32);
      float inv = 1.0f / sm;
#pragma unroll
      for (int r = 0; r < 4; r++) { a1[r] *= inv; dacc[r] += a1[r]; }
    }
    if (write_attn) {
#pragma unroll
      for (int r = 0; r < 4; r++) if (r < nvalid) {
        attn_out[(size_t)(b*11 + grp*4 + r)*4096 + l0 + li]      = a0[r];
        attn_out[(size_t)(b*11 + grp*4 + r)*4096 + l0 + 16 + li] = a1[r];
      }
    }
    // transpose P into LDS (C layout -> A layout), pad rows >= 11 with zeros
#pragma unroll
    for (int r = 0; r < 4; r++) {
      plds[w][grp*4 + r][li]      = (r < nvalid) ? f2bf(a0[r]) : (short)0;
      plds[w][grp*4 + r][16 + li] = (r < nvalid) ? f2bf(a1[r]) : (short)0;
    }
    asm volatile("s_waitcnt lgkmcnt(0)" ::: "memory");
    __builtin_amdgcn_sched_barrier(0);
    s16x8 pa = *(const s16x8*)(&plds[w][li][grp*8]);
    const short* vp = vB + (size_t)b*256*4096 + l0 + grp*8;
#pragma unroll
    for (int st = 0; st < 16; st++) {
      s16x8 bv = *(const s16x8*)(vp + (size_t)(st*16 + li)*4096);
      accu[st] = MFMA_B16(pa, bv, accu[st]);
    }
  }
  // denominator: reduce over the 16 columns of this wave, then atomics
#pragma unroll
  for (int m = 1; m < 16; m <<= 1) {
#pragma unroll
    for (int r = 0; r < 4; r++) dacc[r] += __shfl_xor(dacc[r], m);
  }
  if (li == 0) {
    for (int r = 0; r < nvalid; r++) atomicAdd(&denF[b*11 + grp*4 + r], dacc[r]);
  }
  for (int st = 0; st < 16; st++) {
#pragma unroll
    for (int r = 0; r < 4; r++) if (r < nvalid)
      atomicAdd(&numF[(size_t)(b*11 + grp*4 + r)*256 + st*16 + li], accu[st][r]);
  }
}

// ---------------- updates = num / (den + EPS), cast bf16 ----------------
__global__ __launch_bounds__(256) void finalize_kernel(
    const float* __restrict__ numF, const float* __restrict__ denF, short* __restrict__ updB)
{
  int row = blockIdx.x;
  float d = denF[row] + 1e-8f;
  int i = row*256 + threadIdx.x;
  updB[i] = f2bf(numF[i] / d);
}

// ---------------- fused GRU cell ----------------
// grid (44, 4), block 256. Wave computes 16x16 j-subtile for all 6 gate GEMMs.
__global__ __launch_bounds__(256) void gru_kernel(
    const short* __restrict__ updB, const short* __restrict__ SaB, const float* __restrict__ SaF,
    const short* __restrict__ WiB, const short* __restrict__ WhB,
    const float* __restrict__ bi, const float* __restrict__ bh,
    float* __restrict__ SbF, short* __restrict__ SbB)
{
  const int mt = blockIdx.x;
  const int tid = threadIdx.x;
  const int w = tid >> 6, lane = tid & 63, grp = lane >> 4, li = lane & 15;
  const int j0 = blockIdx.y*64 + w*16;
  s16x8 au[8], as_[8];
  {
    const short* up = updB + (size_t)(mt*16 + li)*256 + grp*8;
    const short* sp = SaB + (size_t)(mt*16 + li)*256 + grp*8;
#pragma unroll
    for (int kt = 0; kt < 8; kt++) { au[kt] = *(const s16x8*)(up + kt*32); as_[kt] = *(const s16x8*)(sp + kt*32); }
  }
  f32x4 ai[3], ah[3];
  for (int gg = 0; gg < 3; gg++) {
    f32x4 ci = {0,0,0,0}, ch = {0,0,0,0};
    const short* wip = WiB + (size_t)(gg*256 + j0 + li)*256 + grp*8;
    const short* whp = WhB + (size_t)(gg*256 + j0 + li)*256 + grp*8;
#pragma unroll
    for (int kt = 0; kt < 8; kt++) {
      ci = MFMA_B16(au[kt],  *(const s16x8*)(wip + kt*32), ci);
      ch = MFMA_B16(as_[kt], *(const s16x8*)(whp + kt*32), ch);
    }
    ai[gg] = ci; ah[gg] = ch;
  }
  const int j = j0 + li;
#pragma unroll
  for (int r = 0; r < 4; r++) {
    const int row = mt*16 + grp*4 + r;
    float ir = ai[0][r] + bi[j],       hr = ah[0][r] + bh[j];
    float iz = ai[1][r] + bi[256 + j], hz = ah[1][r] + bh[256 + j];
    float in_= ai[2][r] + bi[512 + j], hn = ah[2][r] + bh[512 + j];
    float rg = 1.0f / (1.0f + __expf(-(ir + hr)));
    float zg = 1.0f / (1.0f + __expf(-(iz + hz)));
    float ng = tanhf(in_ + rg*hn);
    float nv = (1.0f - zg)*ng + zg*SaF[(size_t)row*256 + j];
    SbF[(size_t)row*256 + j] = nv;
    SbB[(size_t)row*256 + j] = f2bf(nv);
  }
}

// ---------------- LN + W1 + relu ----------------
// grid (44, 16), block 256
__global__ __launch_bounds__(256) void mlp1_kernel(
    const float* __restrict__ SbF, const float* __restrict__ lng, const float* __restrict__ lnb,
    const short* __restrict__ W1B, const float* __restrict__ b1, short* __restrict__ hidB)
{
  __shared__ float red0[16][16], red1[16][16];
  __shared__ float mu_s[16], rs_s[16];
  __shared__ short hl[16][264];
  const int mt = blockIdx.x, nb = blockIdx.y;
  const int tid = threadIdx.x;
  const int rr = tid & 15, cs = tid >> 4;
  const float* rp = SbF + (size_t)(mt*16 + rr)*256 + cs*16;
  float s = 0.f, ss = 0.f;
#pragma unroll
  for (int i = 0; i < 16; i++) { float x = rp[i]; s += x; ss += x*x; }
  red0[rr][cs] = s; red1[rr][cs] = ss;
  __syncthreads();
  if (tid < 16) {
    float ts = 0.f, tss = 0.f;
#pragma unroll
    for (int i = 0; i < 16; i++) { ts += red0[tid][i]; tss += red1[tid][i]; }
    float mu = ts * 0.00390625f;
    mu_s[tid] = mu; rs_s[tid] = rsqrtf(tss*0.00390625f - mu*mu + 1e-6f);
  }
  __syncthreads();
  {
    float mu = mu_s[rr], rs = rs_s[rr];
#pragma unroll
    for (int i = 0; i < 16; i++) { int c = cs*16 + i; hl[rr][c] = f2bf((rp[i]-mu)*rs*lng[c] + lnb[c]); }
  }
  __syncthreads();
  const int w = tid >> 6, lane = tid & 63, grp = lane >> 4, li = lane & 15;
  const int n = nb*64 + w*16 + li;
  f32x4 acc = {0,0,0,0};
  const short* wp = W1B + (size_t)n*256 + grp*8;
#pragma unroll
  for (int kt = 0; kt < 8; kt++)
    acc = MFMA_B16(*(const s16x8*)(&hl[li][kt*32 + grp*8]), *(const s16x8*)(wp + kt*32), acc);
  const float bias = b1[n];
#pragma unroll
  for (int r = 0; r < 4; r++)
    hidB[(size_t)(mt*16 + grp*4 + r)*1024 + n] = f2bf(fmaxf(acc[r] + bias, 0.0f));
}

// ---------------- W2 + bias + residual ----------------
// grid (44, 4), block 256
__global__ __launch_bounds__(256) void mlp2_kernel(
    const short* __restrict__ hidB, const short* __restrict__ W2B,
    const float* __restrict__ b2, const float* __restrict__ SbF,
    float* __restrict__ SaF, short* __restrict__ SaB,
    float* __restrict__ out_slots, const int write_out)
{
  const int mt = blockIdx.x, nb = blockIdx.y;
  const int tid = threadIdx.x;
  const int w = tid >> 6, lane = tid & 63, grp = lane >> 4, li = lane & 15;
  const int n = nb*64 + w*16 + li;
  f32x4 acc = {0,0,0,0};
  const short* ap = hidB + (size_t)(mt*16 + li)*1024 + grp*8;
  const short* wp = W2B + (size_t)n*1024 + grp*8;
#pragma unroll 8
  for (int kt = 0; kt < 32; kt++)
    acc = MFMA_B16(*(const s16x8*)(ap + kt*32), *(const s16x8*)(wp + kt*32), acc);
  const float bias = b2[n];
#pragma unroll
  for (int r = 0; r < 4; r++) {
    const int row = mt*16 + grp*4 + r;
    float v = acc[r] + bias + SbF[(size_t)row*256 + n];
    SaF[(size_t)row*256 + n] = v;
    SaB[(size_t)row*256 + n] = f2bf(v);
    if (write_out) out_slots[(size_t)row*256 + n] = v;
  }
}

// ---------------- host launch ----------------
extern "C" void kernel_launch(void* const* d_in, const int* in_sizes, int n_in,
                              void* d_out, int out_size, void* d_ws, size_t ws_size,
                              hipStream_t stream) {
  (void)in_sizes; (void)n_in; (void)out_size;
  if (ws_size < WS_NEED) return;  // workspace too small: fail loudly (wrong output) instead of corrupting

  const float* slots   = (const float*)d_in[0];
  const float* inputs  = (const float*)d_in[1];
  const float* ln_in_g = (const float*)d_in[2];
  const float* ln_in_b = (const float*)d_in[3];
  const float* Wk      = (const float*)d_in[4];
  const float* Wv      = (const float*)d_in[5];
  const float* ln_q_g  = (const float*)d_in[6];
  const float* ln_q_b  = (const float*)d_in[7];
  const float* Wq      = (const float*)d_in[8];
  const float* gwi     = (const float*)d_in[9];
  const float* gwh     = (const float*)d_in[10];
  const float* gbi     = (const float*)d_in[11];
  const float* gbh     = (const float*)d_in[12];
  const float* ln_m_g  = (const float*)d_in[13];
  const float* ln_m_b  = (const float*)d_in[14];
  const float* W1      = (const float*)d_in[15];
  const float* b1      = (const float*)d_in[16];
  const float* W2      = (const float*)d_in[17];
  const float* b2      = (const float*)d_in[18];
  float* out = (float*)d_out;

  char* ws = (char*)d_ws;
  short* WkB  = (short*)(ws + OFF_WKB);
  short* WvB  = (short*)(ws + OFF_WVB);
  short* WqB  = (short*)(ws + OFF_WQB);
  short* WiB  = (short*)(ws + OFF_WIB);
  short* WhB  = (short*)(ws + OFF_WHB);
  short* W1B  = (short*)(ws + OFF_W1B);
  short* W2B  = (short*)(ws + OFF_W2B);
  short* qB   = (short*)(ws + OFF_QB);
  short* updB = (short*)(ws + OFF_UPDB);
  float* SaF  = (float*)(ws + OFF_SAF);
  short* SaB  = (short*)(ws + OFF_SAB);
  float* SbF  = (float*)(ws + OFF_SBF);
  short* SbB  = (short*)(ws + OFF_SBB);
  short* hidB = (short*)(ws + OFF_HIDB);
  float* numF = (float*)(ws + OFF_NUM);
  float* denF = (float*)(ws + OFF_DEN);
  short* kB   = (short*)(ws + OFF_KB);
  short* vB   = (short*)(ws + OFF_VB);

  float* attn_out = out + 704*256;  // slots region first, then attn [B,O,L]

  prep_kernel<<<dim3(512), dim3(256), 0, stream>>>(
      Wk, Wv, Wq, gwi, gwh, W1, W2, slots,
      WkB, WvB, WqB, WiB, WhB, W1B, W2B, SaF, SaB);

  kv_kernel<<<dim3(32, 64), dim3(256), 0, stream>>>(
      inputs, ln_in_g, ln_in_b, WkB, WvB, kB, vB);

  for (int t = 0; t < 2; t++) {
    slotpre_kernel<<<dim3(44, 4), dim3(256), 0, stream>>>(
        SaF, ln_q_g, ln_q_b, WqB, qB, numF, denF);
    attn_kernel<<<dim3(8, 64), dim3(256), 0, stream>>>(
        qB, kB, vB, numF, denF, attn_out, (t == 1) ? 1 : 0);
    finalize_kernel<<<dim3(704), dim3(256), 0, stream>>>(numF, denF, updB);
    gru_kernel<<<dim3(44, 4), dim3(256), 0, stream>>>(
        updB, SaB, SaF, WiB, WhB, gbi, gbh, SbF, SbB);
    mlp1_kernel<<<dim3(44, 16), dim3(256), 0, stream>>>(
        SbF, ln_m_g, ln_m_b, W1B, b1, hidB);
    mlp2_kernel<<<dim3(44, 4), dim3(256), 0, stream>>>(
        hidB, W2B, b2, SbF, SaF, SaB, out, (t == 1) ? 1 : 0);
  }
}